// Round 1
// baseline (235.587 us; speedup 1.0000x reference)
//
#include <hip/hip_runtime.h>

// Problem constants (match reference)
#define CCH 256
#define HH  256
#define WW  256
#define NROI 512
#define RBIN 7

// One block per roi. 256 threads: threads 0..195 each own one sample point
// (14 x 14 grid = 7x7 bins x 2x2 samples). Loop over channels innermost so
// the two feature rows a point needs stay L1-resident within one channel
// iteration (per roi-channel working set ~18KB < 32KB L1).
__global__ __launch_bounds__(256)
void roialign_direct_kernel(const float* __restrict__ feat,
                            const float* __restrict__ rois,
                            float* __restrict__ out)
{
    const int n = blockIdx.x;
    const int t = threadIdx.x;

    __shared__ float ptmax[196];
    __shared__ float pooled[RBIN * RBIN];

    // roi layout: [y_start, x_start, y_end, x_end]
    const float y0  = rois[n * 4 + 0];
    const float x0  = rois[n * 4 + 1];
    const float y1e = rois[n * 4 + 2];
    const float x1e = rois[n * 4 + 3];
    const float sh = (y1e - y0) / (float)RBIN;
    const float sw = (x1e - x0) / (float)RBIN;

    const bool active = (t < 196);

    int off11 = 0, off12 = 0, off21 = 0, off22 = 0;
    float wx1 = 0.f, wx2 = 0.f, wy1 = 0.f, wy2 = 0.f;

    if (active) {
        const int py = t / 14;       // y-sample index 0..13
        const int px = t % 14;       // x-sample index 0..13
        const int by = py >> 1, sy = py & 1;
        const int bx = px >> 1, sx = px & 1;

        // match reference arithmetic: base + stride*i + (s+1)*stride/3
        const float y = y0 + sh * (float)by +
                        ((sy == 0) ? (sh / 3.0f) : (2.0f * sh / 3.0f));
        const float x = x0 + sw * (float)bx +
                        ((sx == 0) ? (sw / 3.0f) : (2.0f * sw / 3.0f));

        int iy1 = (int)floorf(y);
        int iy2 = iy1 + 1;
        int ix1 = (int)floorf(x);
        int ix2 = ix1 + 1;
        iy1 = min(max(iy1, 0), HH - 1);
        iy2 = min(max(iy2, 0), HH - 1);
        ix1 = min(max(ix1, 0), WW - 1);
        ix2 = min(max(ix2, 0), WW - 1);

        // weights from CLIPPED indices (matches reference exactly,
        // including the zero-value edge case at y/x in [255,256))
        wy1 = y - (float)iy1;
        wy2 = (float)iy2 - y;
        wx1 = x - (float)ix1;
        wx2 = (float)ix2 - x;

        off11 = iy1 * WW + ix1;
        off12 = iy1 * WW + ix2;
        off21 = iy2 * WW + ix1;
        off22 = iy2 * WW + ix2;
    }

    if (active) {
        float m = -INFINITY;
        const float* f = feat;
        #pragma unroll 4
        for (int c = 0; c < CCH; ++c) {
            const float f11 = f[off11];
            const float f12 = f[off12];
            const float f21 = f[off21];
            const float f22 = f[off22];
            const float p = f11 * wx2 + f12 * wx1;
            const float q = f21 * wx2 + f22 * wx1;
            const float v = p * wy2 + q * wy1;
            m = fmaxf(m, v);
            f += HH * WW;
        }
        ptmax[t] = m;
    }
    __syncthreads();

    // 2x2 sample-points -> bin max
    if (t < RBIN * RBIN) {
        const int by = t / RBIN;
        const int bx = t % RBIN;
        const int p00 = (2 * by) * 14 + 2 * bx;
        const float a = fmaxf(ptmax[p00],      ptmax[p00 + 1]);
        const float b = fmaxf(ptmax[p00 + 14], ptmax[p00 + 15]);
        pooled[t] = fmaxf(a, b);
    }
    __syncthreads();

    // broadcast across channels: out[n][c][by][bx] = pooled[by][bx]
    const int total = CCH * RBIN * RBIN;          // 12544
    float* o = out + (size_t)n * (size_t)total;
    for (int idx = t; idx < total; idx += 256) {
        o[idx] = pooled[idx % (RBIN * RBIN)];
    }
}

extern "C" void kernel_launch(void* const* d_in, const int* in_sizes, int n_in,
                              void* d_out, int out_size, void* d_ws, size_t ws_size,
                              hipStream_t stream)
{
    const float* feat = (const float*)d_in[0];   // (256, 256, 256) fp32
    const float* rois = (const float*)d_in[1];   // (512, 4) fp32
    float* out = (float*)d_out;                  // (512, 256, 7, 7) fp32

    roialign_direct_kernel<<<NROI, 256, 0, stream>>>(feat, rois, out);
}

// Round 2
// 139.078 us; speedup vs baseline: 1.6939x; 1.6939x over previous
//
#include <hip/hip_runtime.h>

#define CCH 256
#define HH  256
#define WW  256
#define HWSZ (HH * WW)
#define NROI 512
#define RBIN 7
#define NBIN (RBIN * RBIN)          // 49
#define TFEAT_BYTES ((size_t)HWSZ * CCH * 2)          // 32 MiB bf16 HWC
#define POOLED_BYTES ((size_t)NROI * NBIN * 4)        // 100 KB

__device__ __forceinline__ unsigned short f2bf_rne(float f) {
    unsigned u = __float_as_uint(f);
    u = (u + 0x7fffu + ((u >> 16) & 1u)) >> 16;
    return (unsigned short)u;
}
__device__ __forceinline__ float bf2f(unsigned short h) {
    return __uint_as_float(((unsigned)h) << 16);
}

// ---------------- Kernel 1: (C,H,W) fp32 -> (H,W,C) bf16 transpose ----------
// grid (HW/32, C/32) = (2048, 8), block (32, 8), 4 elements/thread.
__global__ __launch_bounds__(256)
void transpose_chw_to_hwc_bf16(const float* __restrict__ feat,
                               unsigned short* __restrict__ tfeat)
{
    __shared__ float tile[32][33];
    const int tx = threadIdx.x;         // 0..31
    const int ty = threadIdx.y;         // 0..7
    const int hw0 = blockIdx.x * 32;
    const int c0  = blockIdx.y * 32;

    #pragma unroll
    for (int j = 0; j < 4; ++j) {
        const int c = c0 + ty + j * 8;
        tile[ty + j * 8][tx] = feat[(size_t)c * HWSZ + hw0 + tx]; // coalesced read
    }
    __syncthreads();
    #pragma unroll
    for (int j = 0; j < 4; ++j) {
        const int hw = hw0 + ty + j * 8;
        const int c  = c0 + tx;
        tfeat[(size_t)hw * CCH + c] = f2bf_rne(tile[tx][ty + j * 8]); // coalesced write
    }
}

// ---------------- Kernel 2: sampling, one block per (roi, bin) --------------
// 256 threads = 4 waves; wave w owns sample point (sy=w>>1, sx=w&1);
// lane l handles channels 4l..4l+3 (ushort4 per corner, coalesced).
__global__ __launch_bounds__(256)
void roialign_sample_hwc(const unsigned short* __restrict__ tfeat,
                         const float* __restrict__ rois,
                         float* __restrict__ pooled)
{
    const int blk = blockIdx.x;
    const int n   = blk / NBIN;
    const int bin = blk % NBIN;
    const int by  = bin / RBIN;
    const int bx  = bin % RBIN;

    const int t    = threadIdx.x;
    const int wave = t >> 6;
    const int lane = t & 63;
    const int sy   = wave >> 1;
    const int sx   = wave & 1;

    const float y0  = rois[n * 4 + 0];
    const float x0  = rois[n * 4 + 1];
    const float sh  = (rois[n * 4 + 2] - y0) / (float)RBIN;
    const float sw  = (rois[n * 4 + 3] - x0) / (float)RBIN;

    const float y = y0 + sh * (float)by +
                    ((sy == 0) ? (sh / 3.0f) : (2.0f * sh / 3.0f));
    const float x = x0 + sw * (float)bx +
                    ((sx == 0) ? (sw / 3.0f) : (2.0f * sw / 3.0f));

    int iy1 = (int)floorf(y);
    int iy2 = iy1 + 1;
    int ix1 = (int)floorf(x);
    int ix2 = ix1 + 1;
    iy1 = min(max(iy1, 0), HH - 1);
    iy2 = min(max(iy2, 0), HH - 1);
    ix1 = min(max(ix1, 0), WW - 1);
    ix2 = min(max(ix2, 0), WW - 1);

    // weights from clipped indices — matches reference (incl. zero strip)
    const float wy1 = y - (float)iy1;
    const float wy2 = (float)iy2 - y;
    const float wx1 = x - (float)ix1;
    const float wx2 = (float)ix2 - x;

    const ushort4* p11 = (const ushort4*)(tfeat + (size_t)(iy1 * WW + ix1) * CCH);
    const ushort4* p12 = (const ushort4*)(tfeat + (size_t)(iy1 * WW + ix2) * CCH);
    const ushort4* p21 = (const ushort4*)(tfeat + (size_t)(iy2 * WW + ix1) * CCH);
    const ushort4* p22 = (const ushort4*)(tfeat + (size_t)(iy2 * WW + ix2) * CCH);

    const ushort4 a = p11[lane];
    const ushort4 b = p12[lane];
    const ushort4 c = p21[lane];
    const ushort4 d = p22[lane];

    float m = -INFINITY;
    {
        float p, q, v;
        p = bf2f(a.x) * wx2 + bf2f(b.x) * wx1;
        q = bf2f(c.x) * wx2 + bf2f(d.x) * wx1;
        v = p * wy2 + q * wy1;  m = fmaxf(m, v);
        p = bf2f(a.y) * wx2 + bf2f(b.y) * wx1;
        q = bf2f(c.y) * wx2 + bf2f(d.y) * wx1;
        v = p * wy2 + q * wy1;  m = fmaxf(m, v);
        p = bf2f(a.z) * wx2 + bf2f(b.z) * wx1;
        q = bf2f(c.z) * wx2 + bf2f(d.z) * wx1;
        v = p * wy2 + q * wy1;  m = fmaxf(m, v);
        p = bf2f(a.w) * wx2 + bf2f(b.w) * wx1;
        q = bf2f(c.w) * wx2 + bf2f(d.w) * wx1;
        v = p * wy2 + q * wy1;  m = fmaxf(m, v);
    }

    // wave butterfly max (64 lanes)
    #pragma unroll
    for (int off = 32; off > 0; off >>= 1)
        m = fmaxf(m, __shfl_xor(m, off, 64));

    __shared__ float wmax[4];
    if (lane == 0) wmax[wave] = m;
    __syncthreads();
    if (t == 0) {
        float r = fmaxf(fmaxf(wmax[0], wmax[1]), fmaxf(wmax[2], wmax[3]));
        pooled[n * NBIN + bin] = r;
    }
}

// ---------------- Kernel 3: broadcast pooled -> (N, C, 7, 7) ----------------
__global__ __launch_bounds__(256)
void roialign_broadcast(const float* __restrict__ pooled,
                        float* __restrict__ out)
{
    const int n = blockIdx.x;
    const int t = threadIdx.x;
    __shared__ float p[NBIN];
    if (t < NBIN) p[t] = pooled[n * NBIN + t];
    __syncthreads();
    float* o = out + (size_t)n * (CCH * NBIN);
    for (int idx = t; idx < CCH * NBIN; idx += 256)
        o[idx] = p[idx % NBIN];
}

// ---------------- Fallback (round-1 direct kernel, used if ws too small) ----
__global__ __launch_bounds__(256)
void roialign_direct_kernel(const float* __restrict__ feat,
                            const float* __restrict__ rois,
                            float* __restrict__ out)
{
    const int n = blockIdx.x;
    const int t = threadIdx.x;
    __shared__ float ptmax[196];
    __shared__ float pooled[NBIN];

    const float y0  = rois[n * 4 + 0];
    const float x0  = rois[n * 4 + 1];
    const float sh  = (rois[n * 4 + 2] - y0) / (float)RBIN;
    const float sw  = (rois[n * 4 + 3] - x0) / (float)RBIN;

    const bool active = (t < 196);
    int off11 = 0, off12 = 0, off21 = 0, off22 = 0;
    float wx1 = 0.f, wx2 = 0.f, wy1 = 0.f, wy2 = 0.f;
    if (active) {
        const int py = t / 14, px = t % 14;
        const int by = py >> 1, sy = py & 1;
        const int bx = px >> 1, sx = px & 1;
        const float y = y0 + sh * (float)by + ((sy == 0) ? (sh / 3.0f) : (2.0f * sh / 3.0f));
        const float x = x0 + sw * (float)bx + ((sx == 0) ? (sw / 3.0f) : (2.0f * sw / 3.0f));
        int iy1 = (int)floorf(y), iy2 = iy1 + 1;
        int ix1 = (int)floorf(x), ix2 = ix1 + 1;
        iy1 = min(max(iy1, 0), HH - 1); iy2 = min(max(iy2, 0), HH - 1);
        ix1 = min(max(ix1, 0), WW - 1); ix2 = min(max(ix2, 0), WW - 1);
        wy1 = y - (float)iy1; wy2 = (float)iy2 - y;
        wx1 = x - (float)ix1; wx2 = (float)ix2 - x;
        off11 = iy1 * WW + ix1; off12 = iy1 * WW + ix2;
        off21 = iy2 * WW + ix1; off22 = iy2 * WW + ix2;
    }
    if (active) {
        float m = -INFINITY;
        const float* f = feat;
        #pragma unroll 4
        for (int c = 0; c < CCH; ++c) {
            const float p = f[off11] * wx2 + f[off12] * wx1;
            const float q = f[off21] * wx2 + f[off22] * wx1;
            m = fmaxf(m, p * wy2 + q * wy1);
            f += HWSZ;
        }
        ptmax[t] = m;
    }
    __syncthreads();
    if (t < NBIN) {
        const int by = t / RBIN, bx = t % RBIN;
        const int p00 = (2 * by) * 14 + 2 * bx;
        pooled[t] = fmaxf(fmaxf(ptmax[p00], ptmax[p00 + 1]),
                          fmaxf(ptmax[p00 + 14], ptmax[p00 + 15]));
    }
    __syncthreads();
    float* o = out + (size_t)n * (CCH * NBIN);
    for (int idx = t; idx < CCH * NBIN; idx += 256)
        o[idx] = pooled[idx % NBIN];
}

extern "C" void kernel_launch(void* const* d_in, const int* in_sizes, int n_in,
                              void* d_out, int out_size, void* d_ws, size_t ws_size,
                              hipStream_t stream)
{
    const float* feat = (const float*)d_in[0];   // (256,256,256) fp32
    const float* rois = (const float*)d_in[1];   // (512,4) fp32
    float* out = (float*)d_out;                  // (512,256,7,7) fp32

    if (ws_size < TFEAT_BYTES + POOLED_BYTES) {
        roialign_direct_kernel<<<NROI, 256, 0, stream>>>(feat, rois, out);
        return;
    }

    unsigned short* tfeat = (unsigned short*)d_ws;
    float* pooled = (float*)((char*)d_ws + TFEAT_BYTES);

    dim3 tgrid(HWSZ / 32, CCH / 32);
    dim3 tblk(32, 8);
    transpose_chw_to_hwc_bf16<<<tgrid, tblk, 0, stream>>>(feat, tfeat);

    roialign_sample_hwc<<<NROI * NBIN, 256, 0, stream>>>(tfeat, rois, pooled);

    roialign_broadcast<<<NROI, 256, 0, stream>>>(pooled, out);
}

// Round 5
// 135.651 us; speedup vs baseline: 1.7367x; 1.0253x over previous
//
#include <hip/hip_runtime.h>

#define CCH 256
#define HH  256
#define WW  256
#define HWSZ (HH * WW)
#define NROI 512
#define RBIN 7
#define NBIN (RBIN * RBIN)                    // 49
#define TFEAT_BYTES ((size_t)HWSZ * CCH * 2)  // 32 MiB bf16 HWC

// clang-native vector type: __builtin_nontemporal_load rejects HIP's
// struct-based float2, but accepts ext_vector_type.
typedef float vfloat2 __attribute__((ext_vector_type(2)));

__device__ __forceinline__ unsigned short f2bf_rne(float f) {
    unsigned u = __float_as_uint(f);
    u = (u + 0x7fffu + ((u >> 16) & 1u)) >> 16;
    return (unsigned short)u;
}
__device__ __forceinline__ float bf2f(unsigned short h) {
    return __uint_as_float(((unsigned)h) << 16);
}

// ---------------- Kernel 1: (C,H,W) fp32 -> (H,W,C) bf16 transpose ----------
// grid (HW/64, C/32) = (1024, 8), block 256 (flat).
// Tile = 32 channels x 64 hw. Read: 4 passes of float2 (nontemporal --
// feature is read-once; keep L2 for tfeat), 256 B contiguous per 32-lane
// group. Write: 4 passes of ushort2 along channels, 64 B segments.
// LDS: read-in is 2-way bank aliased, write-out column access is 2-way
// aliased -- both free on CDNA4 (m136).
__global__ __launch_bounds__(256)
void transpose_chw_to_hwc_bf16(const float* __restrict__ feat,
                               unsigned short* __restrict__ tfeat)
{
    __shared__ float tile[32][65];            // [c_local][hw_local]
    const int t   = threadIdx.x;              // 0..255
    const int hw0 = blockIdx.x * 64;
    const int c0  = blockIdx.y * 32;

    #pragma unroll
    for (int j = 0; j < 4; ++j) {
        const int cl = (t >> 5) + j * 8;      // 0..31 over passes
        const int hl = (t & 31) * 2;          // 0,2,..,62
        const vfloat2 v = __builtin_nontemporal_load(
            (const vfloat2*)(feat + (size_t)(c0 + cl) * HWSZ + hw0 + hl));
        tile[cl][hl]     = v.x;
        tile[cl][hl + 1] = v.y;
    }
    __syncthreads();
    #pragma unroll
    for (int j = 0; j < 4; ++j) {
        const int hl = (t >> 4) + j * 16;     // 0..63 over passes
        const int cl = (t & 15) * 2;          // 0,2,..,30
        ushort2 w;
        w.x = f2bf_rne(tile[cl][hl]);
        w.y = f2bf_rne(tile[cl + 1][hl]);
        *(ushort2*)(tfeat + (size_t)(hw0 + hl) * CCH + c0 + cl) = w;
    }
}

// ---------------- Kernel 2: fused sample + pool + broadcast -----------------
// One block per roi: 1024 threads = 16 waves -> exactly 2 blocks/CU,
// 32 waves/CU (full occupancy). Wave owns one of 196 sample points per
// iteration; lane l covers channels 4l..4l+3 (ushort4, coalesced 512B/wave
// per corner). Butterfly max over lanes; LDS combine 2x2 points -> bin;
// coalesced nontemporal broadcast store.
__global__ __launch_bounds__(1024)
void roialign_fused(const unsigned short* __restrict__ tfeat,
                    const float* __restrict__ rois,
                    float* __restrict__ out)
{
    const int n    = blockIdx.x;
    const int t    = threadIdx.x;
    const int wave = t >> 6;                  // 0..15
    const int lane = t & 63;

    __shared__ float pmax[196];
    __shared__ float pooled[NBIN];

    const float y0 = rois[n * 4 + 0];
    const float x0 = rois[n * 4 + 1];
    const float sh = (rois[n * 4 + 2] - y0) / (float)RBIN;
    const float sw = (rois[n * 4 + 3] - x0) / (float)RBIN;

    for (int p = wave; p < 196; p += 16) {
        const int py = p / 14;                // y-sample 0..13
        const int px = p % 14;                // x-sample 0..13
        const int by = py >> 1, sy = py & 1;
        const int bx = px >> 1, sx = px & 1;

        const float y = y0 + sh * (float)by +
                        ((sy == 0) ? (sh / 3.0f) : (2.0f * sh / 3.0f));
        const float x = x0 + sw * (float)bx +
                        ((sx == 0) ? (sw / 3.0f) : (2.0f * sw / 3.0f));

        int iy1 = (int)floorf(y);
        int iy2 = iy1 + 1;
        int ix1 = (int)floorf(x);
        int ix2 = ix1 + 1;
        iy1 = min(max(iy1, 0), HH - 1);
        iy2 = min(max(iy2, 0), HH - 1);
        ix1 = min(max(ix1, 0), WW - 1);
        ix2 = min(max(ix2, 0), WW - 1);

        // weights from clipped indices (matches reference, incl. edge strip)
        const float wy1 = y - (float)iy1;
        const float wy2 = (float)iy2 - y;
        const float wx1 = x - (float)ix1;
        const float wx2 = (float)ix2 - x;

        const ushort4 a = ((const ushort4*)(tfeat + (size_t)(iy1 * WW + ix1) * CCH))[lane];
        const ushort4 b = ((const ushort4*)(tfeat + (size_t)(iy1 * WW + ix2) * CCH))[lane];
        const ushort4 c = ((const ushort4*)(tfeat + (size_t)(iy2 * WW + ix1) * CCH))[lane];
        const ushort4 d = ((const ushort4*)(tfeat + (size_t)(iy2 * WW + ix2) * CCH))[lane];

        float m;
        {
            float pp, qq, v0, v1;
            pp = bf2f(a.x) * wx2 + bf2f(b.x) * wx1;
            qq = bf2f(c.x) * wx2 + bf2f(d.x) * wx1;
            v0 = pp * wy2 + qq * wy1;
            pp = bf2f(a.y) * wx2 + bf2f(b.y) * wx1;
            qq = bf2f(c.y) * wx2 + bf2f(d.y) * wx1;
            v1 = pp * wy2 + qq * wy1;
            m = fmaxf(v0, v1);
            pp = bf2f(a.z) * wx2 + bf2f(b.z) * wx1;
            qq = bf2f(c.z) * wx2 + bf2f(d.z) * wx1;
            v0 = pp * wy2 + qq * wy1;
            pp = bf2f(a.w) * wx2 + bf2f(b.w) * wx1;
            qq = bf2f(c.w) * wx2 + bf2f(d.w) * wx1;
            v1 = pp * wy2 + qq * wy1;
            m = fmaxf(m, fmaxf(v0, v1));
        }

        #pragma unroll
        for (int off = 32; off > 0; off >>= 1)
            m = fmaxf(m, __shfl_xor(m, off, 64));

        if (lane == 0) pmax[p] = m;
    }
    __syncthreads();

    if (t < NBIN) {
        const int by = t / RBIN, bx = t % RBIN;
        const int p00 = (2 * by) * 14 + 2 * bx;
        pooled[t] = fmaxf(fmaxf(pmax[p00],      pmax[p00 + 1]),
                          fmaxf(pmax[p00 + 14], pmax[p00 + 15]));
    }
    __syncthreads();

    float* o = out + (size_t)n * (CCH * NBIN);
    #pragma unroll
    for (int k = 0; k < 13; ++k) {            // 13*1024 >= 12544
        const int idx = t + k * 1024;
        if (idx < CCH * NBIN)
            __builtin_nontemporal_store(pooled[idx % NBIN], o + idx);
    }
}

// ---------------- Fallback (round-1 direct kernel, used if ws too small) ----
__global__ __launch_bounds__(256)
void roialign_direct_kernel(const float* __restrict__ feat,
                            const float* __restrict__ rois,
                            float* __restrict__ out)
{
    const int n = blockIdx.x;
    const int t = threadIdx.x;
    __shared__ float ptmax[196];
    __shared__ float pooled[NBIN];

    const float y0  = rois[n * 4 + 0];
    const float x0  = rois[n * 4 + 1];
    const float sh  = (rois[n * 4 + 2] - y0) / (float)RBIN;
    const float sw  = (rois[n * 4 + 3] - x0) / (float)RBIN;

    const bool active = (t < 196);
    int off11 = 0, off12 = 0, off21 = 0, off22 = 0;
    float wx1 = 0.f, wx2 = 0.f, wy1 = 0.f, wy2 = 0.f;
    if (active) {
        const int py = t / 14, px = t % 14;
        const int by = py >> 1, sy = py & 1;
        const int bx = px >> 1, sx = px & 1;
        const float y = y0 + sh * (float)by + ((sy == 0) ? (sh / 3.0f) : (2.0f * sh / 3.0f));
        const float x = x0 + sw * (float)bx + ((sx == 0) ? (sw / 3.0f) : (2.0f * sw / 3.0f));
        int iy1 = (int)floorf(y), iy2 = iy1 + 1;
        int ix1 = (int)floorf(x), ix2 = ix1 + 1;
        iy1 = min(max(iy1, 0), HH - 1); iy2 = min(max(iy2, 0), HH - 1);
        ix1 = min(max(ix1, 0), WW - 1); ix2 = min(max(ix2, 0), WW - 1);
        wy1 = y - (float)iy1; wy2 = (float)iy2 - y;
        wx1 = x - (float)ix1; wx2 = (float)ix2 - x;
        off11 = iy1 * WW + ix1; off12 = iy1 * WW + ix2;
        off21 = iy2 * WW + ix1; off22 = iy2 * WW + ix2;
    }
    if (active) {
        float m = -INFINITY;
        const float* f = feat;
        #pragma unroll 4
        for (int c = 0; c < CCH; ++c) {
            const float p = f[off11] * wx2 + f[off12] * wx1;
            const float q = f[off21] * wx2 + f[off22] * wx1;
            m = fmaxf(m, p * wy2 + q * wy1);
            f += HWSZ;
        }
        ptmax[t] = m;
    }
    __syncthreads();
    if (t < NBIN) {
        const int by = t / RBIN, bx = t % RBIN;
        const int p00 = (2 * by) * 14 + 2 * bx;
        pooled[t] = fmaxf(fmaxf(ptmax[p00], ptmax[p00 + 1]),
                          fmaxf(ptmax[p00 + 14], ptmax[p00 + 15]));
    }
    __syncthreads();
    float* o = out + (size_t)n * (CCH * NBIN);
    for (int idx = t; idx < CCH * NBIN; idx += 256)
        o[idx] = pooled[idx % NBIN];
}

extern "C" void kernel_launch(void* const* d_in, const int* in_sizes, int n_in,
                              void* d_out, int out_size, void* d_ws, size_t ws_size,
                              hipStream_t stream)
{
    const float* feat = (const float*)d_in[0];   // (256,256,256) fp32
    const float* rois = (const float*)d_in[1];   // (512,4) fp32
    float* out = (float*)d_out;                  // (512,256,7,7) fp32

    if (ws_size < TFEAT_BYTES) {
        roialign_direct_kernel<<<NROI, 256, 0, stream>>>(feat, rois, out);
        return;
    }

    unsigned short* tfeat = (unsigned short*)d_ws;

    dim3 tgrid(HWSZ / 64, CCH / 32);
    transpose_chw_to_hwc_bf16<<<tgrid, 256, 0, stream>>>(feat, tfeat);

    roialign_fused<<<NROI, 1024, 0, stream>>>(tfeat, rois, out);
}

// Round 6
// 131.786 us; speedup vs baseline: 1.7877x; 1.0293x over previous
//
#include <hip/hip_runtime.h>

#define CCH 256
#define HH  256
#define WW  256
#define HWSZ (HH * WW)
#define NROI 512
#define RBIN 7
#define NBIN (RBIN * RBIN)                    // 49
#define TFEAT_BYTES ((size_t)HWSZ * CCH * 2)  // 32 MiB bf16 HWC

// clang-native vector types: __builtin_nontemporal_load rejects HIP's
// struct-based vector types, but accepts ext_vector_type.
typedef float vfloat4 __attribute__((ext_vector_type(4)));

__device__ __forceinline__ unsigned short f2bf_rne(float f) {
    unsigned u = __float_as_uint(f);
    u = (u + 0x7fffu + ((u >> 16) & 1u)) >> 16;
    return (unsigned short)u;
}

// ---------------- Kernel 1: (C,H,W) fp32 -> (H,W,C) bf16 transpose ----------
// grid (HW/64, C/64) = (1024, 4), block 256 (flat). Tile = 64c x 64hw.
// Read: float4 nontemporal (feature is read-once; keep L2/L3 for tfeat),
// 256 B contiguous per 16-lane group. Write: ushort4 along channels ->
// 128 B (full line) per 16-lane group. LDS column reads are 2 lanes/bank
// (free on CDNA4, m136).
__global__ __launch_bounds__(256)
void transpose_chw_to_hwc_bf16(const float* __restrict__ feat,
                               unsigned short* __restrict__ tfeat)
{
    __shared__ float tile[64][65];            // [c_local][hw_local], 16.6 KB
    const int t   = threadIdx.x;              // 0..255
    const int hw0 = blockIdx.x * 64;
    const int c0  = blockIdx.y * 64;

    #pragma unroll
    for (int j = 0; j < 4; ++j) {
        const int cl = (t >> 4) + j * 16;     // 0..63 over passes
        const int hl = (t & 15) * 4;          // 0,4,..,60
        const vfloat4 v = __builtin_nontemporal_load(
            (const vfloat4*)(feat + (size_t)(c0 + cl) * HWSZ + hw0 + hl));
        tile[cl][hl]     = v.x;
        tile[cl][hl + 1] = v.y;
        tile[cl][hl + 2] = v.z;
        tile[cl][hl + 3] = v.w;
    }
    __syncthreads();
    #pragma unroll
    for (int j = 0; j < 4; ++j) {
        const int hl = (t >> 4) + j * 16;     // 0..63 over passes
        const int cl = (t & 15) * 4;          // 0,4,..,60
        ushort4 w;
        w.x = f2bf_rne(tile[cl][hl]);
        w.y = f2bf_rne(tile[cl + 1][hl]);
        w.z = f2bf_rne(tile[cl + 2][hl]);
        w.w = f2bf_rne(tile[cl + 3][hl]);
        *(ushort4*)(tfeat + (size_t)(hw0 + hl) * CCH + c0 + cl) = w;
    }
}

// ---------------- Kernel 2: fused sample + pool + broadcast -----------------
// One block per roi: 1024 threads = 16 waves (2 blocks/CU, 32 waves/CU).
// Wave owns a whole bin (2x2 sample points): half-wave (32 lanes x 8ch
// uint4 = 256 ch) owns one point; 2 iterations cover the 4 points.
// Per-lane register max across points, ONE 6-step butterfly per bin
// (49 chains/block vs 196 in the point-per-wave version), 16 B/lane loads.
__global__ __launch_bounds__(1024)
void roialign_fused(const unsigned short* __restrict__ tfeat,
                    const float* __restrict__ rois,
                    float* __restrict__ out)
{
    const int n    = blockIdx.x;
    const int t    = threadIdx.x;
    const int wave = t >> 6;                  // 0..15
    const int lane = t & 63;
    const int half = lane >> 5;               // point selector within pair
    const int cOff = (lane & 31) * 8;         // 8 channels per lane

    __shared__ float pooled[NBIN];

    const float y0 = rois[n * 4 + 0];
    const float x0 = rois[n * 4 + 1];
    const float sh = (rois[n * 4 + 2] - y0) / (float)RBIN;
    const float sw = (rois[n * 4 + 3] - x0) / (float)RBIN;

    for (int bin = wave; bin < NBIN; bin += 16) {
        const int by = bin / RBIN;
        const int bx = bin % RBIN;

        float acc[8];
        #pragma unroll
        for (int k = 0; k < 8; ++k) acc[k] = -INFINITY;

        #pragma unroll
        for (int i = 0; i < 2; ++i) {
            const int point = i * 2 + half;   // 0..3 over (i, half)
            const int sy = point >> 1;
            const int sx = point & 1;

            const float y = y0 + sh * (float)by +
                            ((sy == 0) ? (sh / 3.0f) : (2.0f * sh / 3.0f));
            const float x = x0 + sw * (float)bx +
                            ((sx == 0) ? (sw / 3.0f) : (2.0f * sw / 3.0f));

            int iy1 = (int)floorf(y);
            int iy2 = iy1 + 1;
            int ix1 = (int)floorf(x);
            int ix2 = ix1 + 1;
            iy1 = min(max(iy1, 0), HH - 1);
            iy2 = min(max(iy2, 0), HH - 1);
            ix1 = min(max(ix1, 0), WW - 1);
            ix2 = min(max(ix2, 0), WW - 1);

            // weights from clipped indices (matches reference, incl. edge strip)
            const float wy1 = y - (float)iy1;
            const float wy2 = (float)iy2 - y;
            const float wx1 = x - (float)ix1;
            const float wx2 = (float)ix2 - x;

            const uint4 A = *(const uint4*)(tfeat + (size_t)(iy1 * WW + ix1) * CCH + cOff);
            const uint4 B = *(const uint4*)(tfeat + (size_t)(iy1 * WW + ix2) * CCH + cOff);
            const uint4 C = *(const uint4*)(tfeat + (size_t)(iy2 * WW + ix1) * CCH + cOff);
            const uint4 D = *(const uint4*)(tfeat + (size_t)(iy2 * WW + ix2) * CCH + cOff);
            const unsigned* ap = (const unsigned*)&A;
            const unsigned* bp = (const unsigned*)&B;
            const unsigned* cp = (const unsigned*)&C;
            const unsigned* dp = (const unsigned*)&D;

            #pragma unroll
            for (int k = 0; k < 4; ++k) {
                const unsigned ua = ap[k], ub = bp[k], uc = cp[k], ud = dp[k];
                // low bf16 of the dword
                {
                    const float f11 = __uint_as_float(ua << 16);
                    const float f12 = __uint_as_float(ub << 16);
                    const float f21 = __uint_as_float(uc << 16);
                    const float f22 = __uint_as_float(ud << 16);
                    const float p = f11 * wx2 + f12 * wx1;
                    const float q = f21 * wx2 + f22 * wx1;
                    acc[2 * k] = fmaxf(acc[2 * k], p * wy2 + q * wy1);
                }
                // high bf16 of the dword
                {
                    const float f11 = __uint_as_float(ua & 0xffff0000u);
                    const float f12 = __uint_as_float(ub & 0xffff0000u);
                    const float f21 = __uint_as_float(uc & 0xffff0000u);
                    const float f22 = __uint_as_float(ud & 0xffff0000u);
                    const float p = f11 * wx2 + f12 * wx1;
                    const float q = f21 * wx2 + f22 * wx1;
                    acc[2 * k + 1] = fmaxf(acc[2 * k + 1], p * wy2 + q * wy1);
                }
            }
        }

        // in-lane tree over the 8 channel partials
        float m = fmaxf(fmaxf(fmaxf(acc[0], acc[1]), fmaxf(acc[2], acc[3])),
                        fmaxf(fmaxf(acc[4], acc[5]), fmaxf(acc[6], acc[7])));

        // one butterfly per bin: merges channels AND the two halves (points)
        #pragma unroll
        for (int off = 32; off > 0; off >>= 1)
            m = fmaxf(m, __shfl_xor(m, off, 64));

        if (lane == 0) pooled[bin] = m;
    }
    __syncthreads();

    float* o = out + (size_t)n * (CCH * NBIN);
    #pragma unroll
    for (int k = 0; k < 13; ++k) {            // 13*1024 >= 12544
        const int idx = t + k * 1024;
        if (idx < CCH * NBIN)
            __builtin_nontemporal_store(pooled[idx % NBIN], o + idx);
    }
}

// ---------------- Fallback (round-1 direct kernel, used if ws too small) ----
__global__ __launch_bounds__(256)
void roialign_direct_kernel(const float* __restrict__ feat,
                            const float* __restrict__ rois,
                            float* __restrict__ out)
{
    const int n = blockIdx.x;
    const int t = threadIdx.x;
    __shared__ float ptmax[196];
    __shared__ float pooled[NBIN];

    const float y0  = rois[n * 4 + 0];
    const float x0  = rois[n * 4 + 1];
    const float sh  = (rois[n * 4 + 2] - y0) / (float)RBIN;
    const float sw  = (rois[n * 4 + 3] - x0) / (float)RBIN;

    const bool active = (t < 196);
    int off11 = 0, off12 = 0, off21 = 0, off22 = 0;
    float wx1 = 0.f, wx2 = 0.f, wy1 = 0.f, wy2 = 0.f;
    if (active) {
        const int py = t / 14, px = t % 14;
        const int by = py >> 1, sy = py & 1;
        const int bx = px >> 1, sx = px & 1;
        const float y = y0 + sh * (float)by + ((sy == 0) ? (sh / 3.0f) : (2.0f * sh / 3.0f));
        const float x = x0 + sw * (float)bx + ((sx == 0) ? (sw / 3.0f) : (2.0f * sw / 3.0f));
        int iy1 = (int)floorf(y), iy2 = iy1 + 1;
        int ix1 = (int)floorf(x), ix2 = ix1 + 1;
        iy1 = min(max(iy1, 0), HH - 1); iy2 = min(max(iy2, 0), HH - 1);
        ix1 = min(max(ix1, 0), WW - 1); ix2 = min(max(ix2, 0), WW - 1);
        wy1 = y - (float)iy1; wy2 = (float)iy2 - y;
        wx1 = x - (float)ix1; wx2 = (float)ix2 - x;
        off11 = iy1 * WW + ix1; off12 = iy1 * WW + ix2;
        off21 = iy2 * WW + ix1; off22 = iy2 * WW + ix2;
    }
    if (active) {
        float m = -INFINITY;
        const float* f = feat;
        #pragma unroll 4
        for (int c = 0; c < CCH; ++c) {
            const float p = f[off11] * wx2 + f[off12] * wx1;
            const float q = f[off21] * wx2 + f[off22] * wx1;
            m = fmaxf(m, p * wy2 + q * wy1);
            f += HWSZ;
        }
        ptmax[t] = m;
    }
    __syncthreads();
    if (t < NBIN) {
        const int by = t / RBIN, bx = t % RBIN;
        const int p00 = (2 * by) * 14 + 2 * bx;
        pooled[t] = fmaxf(fmaxf(ptmax[p00], ptmax[p00 + 1]),
                          fmaxf(ptmax[p00 + 14], ptmax[p00 + 15]));
    }
    __syncthreads();
    float* o = out + (size_t)n * (CCH * NBIN);
    for (int idx = t; idx < CCH * NBIN; idx += 256)
        o[idx] = pooled[idx % NBIN];
}

extern "C" void kernel_launch(void* const* d_in, const int* in_sizes, int n_in,
                              void* d_out, int out_size, void* d_ws, size_t ws_size,
                              hipStream_t stream)
{
    const float* feat = (const float*)d_in[0];   // (256,256,256) fp32
    const float* rois = (const float*)d_in[1];   // (512,4) fp32
    float* out = (float*)d_out;                  // (512,256,7,7) fp32

    if (ws_size < TFEAT_BYTES) {
        roialign_direct_kernel<<<NROI, 256, 0, stream>>>(feat, rois, out);
        return;
    }

    unsigned short* tfeat = (unsigned short*)d_ws;

    dim3 tgrid(HWSZ / 64, CCH / 64);
    transpose_chw_to_hwc_bf16<<<tgrid, 256, 0, stream>>>(feat, tfeat);

    roialign_fused<<<NROI, 1024, 0, stream>>>(tfeat, rois, out);
}